// Round 7
// baseline (249.228 us; speedup 1.0000x reference)
//
#include <hip/hip_runtime.h>

#define B_TOTAL 2048
#define CAST    128
#define HDIM    256
#define INDIM   256
#define BM      8
#define GRU_BLOCKS (B_TOTAL / BM)     // 256
#define ROW_F4     (CAST * HDIM / 4)  // 8192 float4 per batch row

typedef float fx4 __attribute__((ext_vector_type(4)));

// ---------------- prep: rowstop flags + weight transpose ----------------
// block 0: set rowstop flags. blocks 1..384: pack weights as
// wt[((k4*3 + gate)*256 + h)*4 + j] = w[(gate*256 + h)*256 + k4*4 + j]
__global__ __launch_bounds__(256) void k_prep(
    const int* __restrict__ story_stop, int n_stop,
    const float* __restrict__ w_ih, const float* __restrict__ w_hh,
    int* rowstop, float* wtI, float* wtH) {
    const int t = threadIdx.x;
    if (blockIdx.x == 0) {
        if (t < n_stop) rowstop[story_stop[t]] = 1;
    } else {
        int id  = blockIdx.x - 1;          // 0..383
        int mat = id / 192;                // 0: w_ih, 1: w_hh
        int rem = id % 192;
        int g   = rem / 64;
        int k4  = rem % 64;
        const float* w = mat ? w_hh : w_ih;
        float*      wt = mat ? wtH  : wtI;
        float4 wv = *(const float4*)(w + ((size_t)(g * HDIM + t) * INDIM + k4 * 4));
        *(float4*)(wt + ((size_t)((k4 * 3 + g) * HDIM + t)) * 4) = wv;
    }
}

// ---------------- GRU + scatter + stop-row zeroing ----------------
// blocks [0, GRU_BLOCKS): GRU on BM rows each; writes out_sel and scatters
//   into out_state (skipping stop rows). blocks [GRU_BLOCKS, +n_stop): zero
//   one stop row each. Scatter targets & stop rows are disjoint.
__global__ __launch_bounds__(256) void k_gru(
    const float* __restrict__ x, const int* __restrict__ batch_idxs,
    const int* __restrict__ actor_ids, const float* __restrict__ state,
    const float* __restrict__ wtI, const float* __restrict__ wtH,
    const float* __restrict__ b_ih, const float* __restrict__ b_hh,
    const int* __restrict__ rowstop, const int* __restrict__ story_stop,
    int n_stop, float* __restrict__ out_sel, float* __restrict__ out_state) {
    __shared__ float xs[BM][INDIM];
    __shared__ float ss[BM][HDIM];
    const int h = threadIdx.x;

    if (blockIdx.x >= GRU_BLOCKS) {
        int zb = blockIdx.x - GRU_BLOCKS;
        if (zb < n_stop) {
            long base = (long)story_stop[zb] * ROW_F4;
            fx4* __restrict__ dst = (fx4*)out_state + base + h;
            const fx4 z = (fx4)(0.f);
            #pragma unroll
            for (int j = 0; j < ROW_F4 / 256; ++j)
                __builtin_nontemporal_store(z, dst + j * 256);
        }
        return;
    }

    const int b0 = blockIdx.x * BM;
    #pragma unroll
    for (int r = 0; r < BM; ++r) {
        int g  = b0 + r;
        int bi = batch_idxs[g];
        int a  = actor_ids[bi];
        a = a < 0 ? 0 : (a > CAST - 1 ? CAST - 1 : a);
        xs[r][h] = x[(size_t)g * INDIM + h];
        ss[r][h] = state[((size_t)bi * CAST + a) * HDIM + h];
    }
    __syncthreads();

    float air[BM], aiz[BM], ain[BM], ahr[BM], ahz[BM], ahn[BM];
    #pragma unroll
    for (int r = 0; r < BM; ++r) { air[r]=0.f; aiz[r]=0.f; ain[r]=0.f; ahr[r]=0.f; ahz[r]=0.f; ahn[r]=0.f; }

    const float4* __restrict__ wtI4 = (const float4*)wtI;
    const float4* __restrict__ wtH4 = (const float4*)wtH;

    for (int k4 = 0; k4 < INDIM / 4; ++k4) {
        float4 wir = wtI4[(k4 * 3 + 0) * HDIM + h];
        float4 wiz = wtI4[(k4 * 3 + 1) * HDIM + h];
        float4 win = wtI4[(k4 * 3 + 2) * HDIM + h];
        float4 whr = wtH4[(k4 * 3 + 0) * HDIM + h];
        float4 whz = wtH4[(k4 * 3 + 1) * HDIM + h];
        float4 whn = wtH4[(k4 * 3 + 2) * HDIM + h];
        #pragma unroll
        for (int r = 0; r < BM; ++r) {
            float4 xv = *(const float4*)(&xs[r][k4 * 4]);
            float4 sv = *(const float4*)(&ss[r][k4 * 4]);
            air[r] = fmaf(xv.w, wir.w, fmaf(xv.z, wir.z, fmaf(xv.y, wir.y, fmaf(xv.x, wir.x, air[r]))));
            aiz[r] = fmaf(xv.w, wiz.w, fmaf(xv.z, wiz.z, fmaf(xv.y, wiz.y, fmaf(xv.x, wiz.x, aiz[r]))));
            ain[r] = fmaf(xv.w, win.w, fmaf(xv.z, win.z, fmaf(xv.y, win.y, fmaf(xv.x, win.x, ain[r]))));
            ahr[r] = fmaf(sv.w, whr.w, fmaf(sv.z, whr.z, fmaf(sv.y, whr.y, fmaf(sv.x, whr.x, ahr[r]))));
            ahz[r] = fmaf(sv.w, whz.w, fmaf(sv.z, whz.z, fmaf(sv.y, whz.y, fmaf(sv.x, whz.x, ahz[r]))));
            ahn[r] = fmaf(sv.w, whn.w, fmaf(sv.z, whn.z, fmaf(sv.y, whn.y, fmaf(sv.x, whn.x, ahn[r]))));
        }
    }

    const float bir = b_ih[h], biz = b_ih[HDIM + h], bin = b_ih[2 * HDIM + h];
    const float bhr = b_hh[h], bhz = b_hh[HDIM + h], bhn = b_hh[2 * HDIM + h];

    #pragma unroll
    for (int r = 0; r < BM; ++r) {
        int g  = b0 + r;
        int bi = batch_idxs[g];
        int a  = actor_ids[bi];
        a = a < 0 ? 0 : (a > CAST - 1 ? CAST - 1 : a);
        float ir = air[r] + bir, iz = aiz[r] + biz, inn = ain[r] + bin;
        float hr = ahr[r] + bhr, hz = ahz[r] + bhz, hn = ahn[r] + bhn;
        float rr = 1.f / (1.f + __expf(-(ir + hr)));
        float zz = 1.f / (1.f + __expf(-(iz + hz)));
        float nn = tanhf(inn + rr * hn);
        float val = (1.f - zz) * nn + zz * ss[r][h];
        out_sel[(size_t)g * HDIM + h] = val;
        if (!rowstop[bi]) out_state[((size_t)bi * CAST + a) * HDIM + h] = val;
    }
}

extern "C" void kernel_launch(void* const* d_in, const int* in_sizes, int n_in,
                              void* d_out, int out_size, void* d_ws, size_t ws_size,
                              hipStream_t stream) {
    const float* x          = (const float*)d_in[0];
    const int*   batch_idxs = (const int*)d_in[1];
    const int*   actor_ids  = (const int*)d_in[2];
    const int*   story_stop = (const int*)d_in[3];
    const float* state      = (const float*)d_in[4];
    const float* w_ih       = (const float*)d_in[5];
    const float* w_hh       = (const float*)d_in[6];
    const float* b_ih       = (const float*)d_in[7];
    const float* b_hh       = (const float*)d_in[8];
    const int    n_stop     = in_sizes[3];

    float* out_sel   = (float*)d_out;
    float* out_state = out_sel + (size_t)B_TOTAL * HDIM;

    int*   rowstop = (int*)d_ws;
    float* wtI     = (float*)((char*)d_ws + 16384);
    float* wtH     = wtI + (size_t)3 * HDIM * INDIM;

    hipMemsetAsync(rowstop, 0, B_TOTAL * sizeof(int), stream);
    k_prep<<<1 + 384, 256, 0, stream>>>(story_stop, n_stop, w_ih, w_hh,
                                        rowstop, wtI, wtH);
    // Vendor-tuned bulk copy: state -> out_state (256 MB).
    hipMemcpyAsync(out_state, state, (size_t)B_TOTAL * CAST * HDIM * sizeof(float),
                   hipMemcpyDeviceToDevice, stream);
    k_gru<<<GRU_BLOCKS + 128, 256, 0, stream>>>(
        x, batch_idxs, actor_ids, state, wtI, wtH, b_ih, b_hh,
        rowstop, story_stop, n_stop, out_sel, out_state);
}

// Round 8
// 216.812 us; speedup vs baseline: 1.1495x; 1.1495x over previous
//
#include <hip/hip_runtime.h>

#define B_TOTAL 2048
#define CAST    128
#define HDIM    256
#define INDIM   256
#define BM      8
#define GRU_BLOCKS  (B_TOTAL / BM)    // 256
#define COPY_BLOCKS B_TOTAL           // 2048: one block per batch row
#define ROW_FLOATS  (CAST * HDIM)     // 32768 floats = 128 KB per row

typedef float fx4 __attribute__((ext_vector_type(4)));

// Async global->LDS DMA, 16B per lane. LDS dest is wave-uniform base + lane*16.
__device__ __forceinline__ void gld_lds16(const float* g, float* l) {
    __builtin_amdgcn_global_load_lds(
        (const __attribute__((address_space(1))) void*)g,
        (__attribute__((address_space(3))) void*)l, 16, 0, 0);
}

// ---------------- prep: rowaid/rowstop tables + weight transpose ----------------
// blocks 0..7: rowaid[row]=clamped actor id, rowstop flags.
// blocks 8..391: wt[((k4*3 + gate)*256 + h)*4 + j] = w[(gate*256 + h)*256 + k4*4 + j]
__global__ __launch_bounds__(256) void k_prep(
    const int* __restrict__ batch_idxs, const int* __restrict__ actor_ids,
    const int* __restrict__ story_stop, int n_stop,
    const float* __restrict__ w_ih, const float* __restrict__ w_hh,
    int* rowaid, int* rowstop, float* wtI, float* wtH) {
    const int t = threadIdx.x;
    if (blockIdx.x < 8) {
        int g = blockIdx.x * 256 + t;
        int row = batch_idxs[g];
        int a = actor_ids[row];
        a = a < 0 ? 0 : (a > CAST - 1 ? CAST - 1 : a);
        rowaid[row] = a;
        if (g < n_stop) rowstop[story_stop[g]] = 1;
    } else {
        int id  = blockIdx.x - 8;          // 0..383
        int mat = id / 192;                // 0: w_ih, 1: w_hh
        int rem = id % 192;
        int g   = rem / 64;
        int k4  = rem % 64;
        const float* w = mat ? w_hh : w_ih;
        float*      wt = mat ? wtH  : wtI;
        float4 wv = *(const float4*)(w + ((size_t)(g * HDIM + t) * INDIM + k4 * 4));
        *(float4*)(wt + ((size_t)((k4 * 3 + g) * HDIM + t)) * 4) = wv;
    }
}

// ---------------- fused: LDS-DMA state copy + GRU ----------------
// blocks [0, COPY_BLOCKS): one batch row each. Per wave: quarter-row (32 KB),
//   pipeline 8x global_load_lds (8 KB in flight, zero VGPR cost) -> vmcnt(0)
//   -> 8x ds_read_b128 + store. Skip the (row, aid) 1KB slot (wave-scalar).
//   Stop rows are pure zero-fills.
// blocks [COPY_BLOCKS, +GRU_BLOCKS): GRU on BM rows each; writes out_sel and
//   scatters into out_state (skipping stop rows). Writes disjoint from copy.
__global__ __launch_bounds__(256) void k_main(
    const float* __restrict__ x, const int* __restrict__ batch_idxs,
    const int* __restrict__ actor_ids, const float* __restrict__ state,
    const float* __restrict__ wtI, const float* __restrict__ wtH,
    const float* __restrict__ b_ih, const float* __restrict__ b_hh,
    const int* __restrict__ rowaid, const int* __restrict__ rowstop,
    float* __restrict__ out_sel, float* __restrict__ out_state) {
    __shared__ float smem[8192];          // 32 KB: copy = 4 waves x 8 KB; GRU = xs+ss
    const int h = threadIdx.x;

    if (blockIdx.x < COPY_BLOCKS) {
        const int  b    = blockIdx.x;
        const int  w    = h >> 6;
        const int  lane = h & 63;
        const long qbase = (long)b * ROW_FLOATS + (long)w * 8192;  // quarter-row
        float* __restrict__ dst = out_state + qbase + lane * 4;

        if (rowstop[b]) {
            const fx4 z = (fx4)(0.f);
            #pragma unroll
            for (int op = 0; op < 32; ++op)
                __builtin_nontemporal_store(z, (fx4*)(dst + op * 256));
            return;
        }

        const float* __restrict__ src = state + qbase + lane * 4;
        float* lw = smem + w * 2048;                     // this wave's 8 KB
        const int aid = __builtin_amdgcn_readfirstlane(rowaid[b]);
        const int sk  = aid - w * 32;                    // local op to skip if 0..31

        #pragma unroll
        for (int bt = 0; bt < 4; ++bt) {
            #pragma unroll
            for (int k = 0; k < 8; ++k)
                gld_lds16(src + (bt * 8 + k) * 256, lw + k * 256);
            asm volatile("s_waitcnt vmcnt(0)" ::: "memory");
            __builtin_amdgcn_sched_barrier(0);
            #pragma unroll
            for (int k = 0; k < 8; ++k) {
                const int op = bt * 8 + k;
                if (op != sk) {
                    fx4 v = *(const fx4*)(lw + k * 256 + lane * 4);
                    *(fx4*)(dst + op * 256) = v;
                }
            }
        }
        return;
    }

    // ---------------- GRU ----------------
    float (*xs)[INDIM] = (float(*)[INDIM])smem;
    float (*ss)[HDIM]  = (float(*)[HDIM])(smem + BM * INDIM);
    const int b0 = (blockIdx.x - COPY_BLOCKS) * BM;

    #pragma unroll
    for (int r = 0; r < BM; ++r) {
        int g  = b0 + r;
        int bi = batch_idxs[g];
        int a  = actor_ids[bi];
        a = a < 0 ? 0 : (a > CAST - 1 ? CAST - 1 : a);
        xs[r][h] = x[(size_t)g * INDIM + h];
        ss[r][h] = state[((size_t)bi * CAST + a) * HDIM + h];
    }
    __syncthreads();

    float air[BM], aiz[BM], ain[BM], ahr[BM], ahz[BM], ahn[BM];
    #pragma unroll
    for (int r = 0; r < BM; ++r) { air[r]=0.f; aiz[r]=0.f; ain[r]=0.f; ahr[r]=0.f; ahz[r]=0.f; ahn[r]=0.f; }

    const float4* __restrict__ wtI4 = (const float4*)wtI;
    const float4* __restrict__ wtH4 = (const float4*)wtH;

    for (int k4 = 0; k4 < INDIM / 4; ++k4) {
        float4 wir = wtI4[(k4 * 3 + 0) * HDIM + h];
        float4 wiz = wtI4[(k4 * 3 + 1) * HDIM + h];
        float4 win = wtI4[(k4 * 3 + 2) * HDIM + h];
        float4 whr = wtH4[(k4 * 3 + 0) * HDIM + h];
        float4 whz = wtH4[(k4 * 3 + 1) * HDIM + h];
        float4 whn = wtH4[(k4 * 3 + 2) * HDIM + h];
        #pragma unroll
        for (int r = 0; r < BM; ++r) {
            float4 xv = *(const float4*)(&xs[r][k4 * 4]);
            float4 sv = *(const float4*)(&ss[r][k4 * 4]);
            air[r] = fmaf(xv.w, wir.w, fmaf(xv.z, wir.z, fmaf(xv.y, wir.y, fmaf(xv.x, wir.x, air[r]))));
            aiz[r] = fmaf(xv.w, wiz.w, fmaf(xv.z, wiz.z, fmaf(xv.y, wiz.y, fmaf(xv.x, wiz.x, aiz[r]))));
            ain[r] = fmaf(xv.w, win.w, fmaf(xv.z, win.z, fmaf(xv.y, win.y, fmaf(xv.x, win.x, ain[r]))));
            ahr[r] = fmaf(sv.w, whr.w, fmaf(sv.z, whr.z, fmaf(sv.y, whr.y, fmaf(sv.x, whr.x, ahr[r]))));
            ahz[r] = fmaf(sv.w, whz.w, fmaf(sv.z, whz.z, fmaf(sv.y, whz.y, fmaf(sv.x, whz.x, ahz[r]))));
            ahn[r] = fmaf(sv.w, whn.w, fmaf(sv.z, whn.z, fmaf(sv.y, whn.y, fmaf(sv.x, whn.x, ahn[r]))));
        }
    }

    const float bir = b_ih[h], biz = b_ih[HDIM + h], bin = b_ih[2 * HDIM + h];
    const float bhr = b_hh[h], bhz = b_hh[HDIM + h], bhn = b_hh[2 * HDIM + h];

    #pragma unroll
    for (int r = 0; r < BM; ++r) {
        int g  = b0 + r;
        int bi = batch_idxs[g];
        int a  = actor_ids[bi];
        a = a < 0 ? 0 : (a > CAST - 1 ? CAST - 1 : a);
        float ir = air[r] + bir, iz = aiz[r] + biz, inn = ain[r] + bin;
        float hr = ahr[r] + bhr, hz = ahz[r] + bhz, hn = ahn[r] + bhn;
        float rr = 1.f / (1.f + __expf(-(ir + hr)));
        float zz = 1.f / (1.f + __expf(-(iz + hz)));
        float nn = tanhf(inn + rr * hn);
        float val = (1.f - zz) * nn + zz * ss[r][h];
        out_sel[(size_t)g * HDIM + h] = val;
        if (!rowstop[bi]) out_state[((size_t)bi * CAST + a) * HDIM + h] = val;
    }
}

extern "C" void kernel_launch(void* const* d_in, const int* in_sizes, int n_in,
                              void* d_out, int out_size, void* d_ws, size_t ws_size,
                              hipStream_t stream) {
    const float* x          = (const float*)d_in[0];
    const int*   batch_idxs = (const int*)d_in[1];
    const int*   actor_ids  = (const int*)d_in[2];
    const int*   story_stop = (const int*)d_in[3];
    const float* state      = (const float*)d_in[4];
    const float* w_ih       = (const float*)d_in[5];
    const float* w_hh       = (const float*)d_in[6];
    const float* b_ih       = (const float*)d_in[7];
    const float* b_hh       = (const float*)d_in[8];
    const int    n_stop     = in_sizes[3];

    float* out_sel   = (float*)d_out;
    float* out_state = out_sel + (size_t)B_TOTAL * HDIM;

    int*   rowaid  = (int*)d_ws;
    int*   rowstop = rowaid + B_TOTAL;
    float* wtI     = (float*)((char*)d_ws + 16384);   // 2048*4*2 = 16384
    float* wtH     = wtI + (size_t)3 * HDIM * INDIM;  // 768 KB each

    hipMemsetAsync(rowaid, 0xFF, B_TOTAL * sizeof(int), stream);   // -1
    hipMemsetAsync(rowstop, 0, B_TOTAL * sizeof(int), stream);
    k_prep<<<8 + 384, 256, 0, stream>>>(batch_idxs, actor_ids, story_stop, n_stop,
                                        w_ih, w_hh, rowaid, rowstop, wtI, wtH);
    k_main<<<COPY_BLOCKS + GRU_BLOCKS, 256, 0, stream>>>(
        x, batch_idxs, actor_ids, state, wtI, wtH, b_ih, b_hh,
        rowaid, rowstop, out_sel, out_state);
}

// Round 9
// 167.029 us; speedup vs baseline: 1.4921x; 1.2980x over previous
//
#include <hip/hip_runtime.h>

#define B_TOTAL 2048
#define CAST    128
#define HDIM    256
#define INDIM   256
#define BM      8
#define GRU_BLOCKS (B_TOTAL / BM)     // 256
#define ROW_F4     (CAST * HDIM / 4)  // 8192 float4 per batch row

typedef float fx4 __attribute__((ext_vector_type(4)));

// 8 streaming system-scope non-temporal 16B loads (bypass/no-allocate caches).
#define LD8(D, SP, J0)                                                         \
  asm volatile(                                                                \
    "global_load_dwordx4 %0, %8,  off sc0 sc1 nt\n\t"                          \
    "global_load_dwordx4 %1, %9,  off sc0 sc1 nt\n\t"                          \
    "global_load_dwordx4 %2, %10, off sc0 sc1 nt\n\t"                          \
    "global_load_dwordx4 %3, %11, off sc0 sc1 nt\n\t"                          \
    "global_load_dwordx4 %4, %12, off sc0 sc1 nt\n\t"                          \
    "global_load_dwordx4 %5, %13, off sc0 sc1 nt\n\t"                          \
    "global_load_dwordx4 %6, %14, off sc0 sc1 nt\n\t"                          \
    "global_load_dwordx4 %7, %15, off sc0 sc1 nt"                              \
    : "=&v"(D[0]), "=&v"(D[1]), "=&v"(D[2]), "=&v"(D[3]),                      \
      "=&v"(D[4]), "=&v"(D[5]), "=&v"(D[6]), "=&v"(D[7])                       \
    : "v"(SP + (J0 + 0) * 256), "v"(SP + (J0 + 1) * 256),                      \
      "v"(SP + (J0 + 2) * 256), "v"(SP + (J0 + 3) * 256),                      \
      "v"(SP + (J0 + 4) * 256), "v"(SP + (J0 + 5) * 256),                      \
      "v"(SP + (J0 + 6) * 256), "v"(SP + (J0 + 7) * 256))

// Drain all outstanding loads; data-ties the 16 results so no consumer can
// be scheduled before the wait (rule-#18-style hazard fence via dataflow).
#define WAIT16(A, B)                                                           \
  asm volatile("s_waitcnt vmcnt(0)"                                            \
    : "+v"(A[0]), "+v"(A[1]), "+v"(A[2]), "+v"(A[3]),                          \
      "+v"(A[4]), "+v"(A[5]), "+v"(A[6]), "+v"(A[7]),                          \
      "+v"(B[0]), "+v"(B[1]), "+v"(B[2]), "+v"(B[3]),                          \
      "+v"(B[4]), "+v"(B[5]), "+v"(B[6]), "+v"(B[7]) :: "memory")

// ---------------- prep: rowaid/rowstop tables + weight transpose ----------------
__global__ __launch_bounds__(256) void k_prep(
    const int* __restrict__ batch_idxs, const int* __restrict__ actor_ids,
    const int* __restrict__ story_stop, int n_stop,
    const float* __restrict__ w_ih, const float* __restrict__ w_hh,
    int* rowaid, int* rowstop, float* wtI, float* wtH) {
    const int t = threadIdx.x;
    if (blockIdx.x < 8) {
        int g = blockIdx.x * 256 + t;
        int row = batch_idxs[g];
        int a = actor_ids[row];
        a = a < 0 ? 0 : (a > CAST - 1 ? CAST - 1 : a);
        rowaid[row] = a;
        if (g < n_stop) rowstop[story_stop[g]] = 1;
    } else {
        int id  = blockIdx.x - 8;          // 0..383
        int mat = id / 192;                // 0: w_ih, 1: w_hh
        int rem = id % 192;
        int g   = rem / 64;
        int k4  = rem % 64;
        const float* w = mat ? w_hh : w_ih;
        float*      wt = mat ? wtH  : wtI;
        float4 wv = *(const float4*)(w + ((size_t)(g * HDIM + t) * INDIM + k4 * 4));
        *(float4*)(wt + ((size_t)((k4 * 3 + g) * HDIM + t)) * 4) = wv;
    }
}

// ---------------- fused GRU + bypass-read state copy ----------------
__global__ __launch_bounds__(256) void k_main(
    const float* __restrict__ x, const int* __restrict__ batch_idxs,
    const int* __restrict__ actor_ids, const float* __restrict__ state,
    const float* __restrict__ wtI, const float* __restrict__ wtH,
    const float* __restrict__ b_ih, const float* __restrict__ b_hh,
    const int* __restrict__ rowaid, const int* __restrict__ rowstop,
    float* __restrict__ out_sel, float* __restrict__ out_state) {
    __shared__ float xs[BM][INDIM];
    __shared__ float ss[BM][HDIM];
    const int h = threadIdx.x;

    if (blockIdx.x < GRU_BLOCKS) {
        const int b0 = blockIdx.x * BM;
        #pragma unroll
        for (int r = 0; r < BM; ++r) {
            int g  = b0 + r;
            int bi = batch_idxs[g];
            int a  = actor_ids[bi];
            a = a < 0 ? 0 : (a > CAST - 1 ? CAST - 1 : a);
            xs[r][h] = x[(size_t)g * INDIM + h];
            ss[r][h] = state[((size_t)bi * CAST + a) * HDIM + h];
        }
        __syncthreads();

        float air[BM], aiz[BM], ain[BM], ahr[BM], ahz[BM], ahn[BM];
        #pragma unroll
        for (int r = 0; r < BM; ++r) { air[r]=0.f; aiz[r]=0.f; ain[r]=0.f; ahr[r]=0.f; ahz[r]=0.f; ahn[r]=0.f; }

        const float4* __restrict__ wtI4 = (const float4*)wtI;
        const float4* __restrict__ wtH4 = (const float4*)wtH;

        for (int k4 = 0; k4 < INDIM / 4; ++k4) {
            float4 wir = wtI4[(k4 * 3 + 0) * HDIM + h];
            float4 wiz = wtI4[(k4 * 3 + 1) * HDIM + h];
            float4 win = wtI4[(k4 * 3 + 2) * HDIM + h];
            float4 whr = wtH4[(k4 * 3 + 0) * HDIM + h];
            float4 whz = wtH4[(k4 * 3 + 1) * HDIM + h];
            float4 whn = wtH4[(k4 * 3 + 2) * HDIM + h];
            #pragma unroll
            for (int r = 0; r < BM; ++r) {
                float4 xv = *(const float4*)(&xs[r][k4 * 4]);
                float4 sv = *(const float4*)(&ss[r][k4 * 4]);
                air[r] = fmaf(xv.w, wir.w, fmaf(xv.z, wir.z, fmaf(xv.y, wir.y, fmaf(xv.x, wir.x, air[r]))));
                aiz[r] = fmaf(xv.w, wiz.w, fmaf(xv.z, wiz.z, fmaf(xv.y, wiz.y, fmaf(xv.x, wiz.x, aiz[r]))));
                ain[r] = fmaf(xv.w, win.w, fmaf(xv.z, win.z, fmaf(xv.y, win.y, fmaf(xv.x, win.x, ain[r]))));
                ahr[r] = fmaf(sv.w, whr.w, fmaf(sv.z, whr.z, fmaf(sv.y, whr.y, fmaf(sv.x, whr.x, ahr[r]))));
                ahz[r] = fmaf(sv.w, whz.w, fmaf(sv.z, whz.z, fmaf(sv.y, whz.y, fmaf(sv.x, whz.x, ahz[r]))));
                ahn[r] = fmaf(sv.w, whn.w, fmaf(sv.z, whn.z, fmaf(sv.y, whn.y, fmaf(sv.x, whn.x, ahn[r]))));
            }
        }

        const float bir = b_ih[h], biz = b_ih[HDIM + h], bin = b_ih[2 * HDIM + h];
        const float bhr = b_hh[h], bhz = b_hh[HDIM + h], bhn = b_hh[2 * HDIM + h];

        #pragma unroll
        for (int r = 0; r < BM; ++r) {
            int g  = b0 + r;
            int bi = batch_idxs[g];
            int a  = actor_ids[bi];
            a = a < 0 ? 0 : (a > CAST - 1 ? CAST - 1 : a);
            float ir = air[r] + bir, iz = aiz[r] + biz, inn = ain[r] + bin;
            float hr = ahr[r] + bhr, hz = ahz[r] + bhz, hn = ahn[r] + bhn;
            float rr = 1.f / (1.f + __expf(-(ir + hr)));
            float zz = 1.f / (1.f + __expf(-(iz + hz)));
            float nn = tanhf(inn + rr * hn);
            float val = (1.f - zz) * nn + zz * ss[r][h];
            out_sel[(size_t)g * HDIM + h] = val;
            if (!rowstop[bi]) out_state[((size_t)bi * CAST + a) * HDIM + h] = val;
        }
    } else {
        const int  b = blockIdx.x - GRU_BLOCKS;     // batch row
        const int  t = threadIdx.x;
        const long base = (long)b * ROW_F4;
        fx4* __restrict__ dp = (fx4*)out_state + base + t;

        if (rowstop[b]) {
            const fx4 z = (fx4)(0.f);
            #pragma unroll
            for (int j = 0; j < 32; ++j)
                __builtin_nontemporal_store(z, dp + j * 256);
            return;
        }

        const fx4* __restrict__ sp = (const fx4*)state + base + t;
        // slot c covered at iteration j by c = j*4 + (t>>6): wave-scalar skip.
        const int aid = __builtin_amdgcn_readfirstlane(rowaid[b]);
        const int w   = __builtin_amdgcn_readfirstlane(t >> 6);
        const int jskip = ((aid & 3) == w) ? (aid >> 2) : -1;

        fx4 dA[8], dB[8];
        #pragma unroll
        for (int q = 0; q < 2; ++q) {
            LD8(dA, sp, q * 16);
            LD8(dB, sp, q * 16 + 8);
            WAIT16(dA, dB);
            #pragma unroll
            for (int k = 0; k < 8; ++k)
                if (q * 16 + k != jskip)
                    __builtin_nontemporal_store(dA[k], dp + (q * 16 + k) * 256);
            #pragma unroll
            for (int k = 0; k < 8; ++k)
                if (q * 16 + 8 + k != jskip)
                    __builtin_nontemporal_store(dB[k], dp + (q * 16 + 8 + k) * 256);
        }
    }
}

extern "C" void kernel_launch(void* const* d_in, const int* in_sizes, int n_in,
                              void* d_out, int out_size, void* d_ws, size_t ws_size,
                              hipStream_t stream) {
    const float* x          = (const float*)d_in[0];
    const int*   batch_idxs = (const int*)d_in[1];
    const int*   actor_ids  = (const int*)d_in[2];
    const int*   story_stop = (const int*)d_in[3];
    const float* state      = (const float*)d_in[4];
    const float* w_ih       = (const float*)d_in[5];
    const float* w_hh       = (const float*)d_in[6];
    const float* b_ih       = (const float*)d_in[7];
    const float* b_hh       = (const float*)d_in[8];
    const int    n_stop     = in_sizes[3];

    float* out_sel   = (float*)d_out;
    float* out_state = out_sel + (size_t)B_TOTAL * HDIM;

    int*   rowaid  = (int*)d_ws;
    int*   rowstop = rowaid + B_TOTAL;
    float* wtI     = (float*)((char*)d_ws + 16384);
    float* wtH     = wtI + (size_t)3 * HDIM * INDIM;

    hipMemsetAsync(rowaid, 0xFF, B_TOTAL * sizeof(int), stream);
    hipMemsetAsync(rowstop, 0, B_TOTAL * sizeof(int), stream);
    k_prep<<<8 + 384, 256, 0, stream>>>(batch_idxs, actor_ids, story_stop, n_stop,
                                        w_ih, w_hh, rowaid, rowstop, wtI, wtH);
    k_main<<<GRU_BLOCKS + B_TOTAL, 256, 0, stream>>>(
        x, batch_idxs, actor_ids, state, wtI, wtH, b_ih, b_hh,
        rowaid, rowstop, out_sel, out_state);
}

// Round 10
// 142.226 us; speedup vs baseline: 1.7523x; 1.1744x over previous
//
#include <hip/hip_runtime.h>

#define B_TOTAL 2048
#define CAST    128
#define HDIM    256
#define INDIM   256
#define BM      8
#define GRU_BLOCKS (B_TOTAL / BM)     // 256
#define ROW_F4     (CAST * HDIM / 4)  // 8192 float4 per batch row

typedef float fx4 __attribute__((ext_vector_type(4)));

// ---------------- prep: rowaid/rowstop tables + weight transpose ----------------
// blocks 0..7: rowaid[row]=clamped actor id (batch_idxs covers all rows),
//              rowstop flags. blocks 8..391: pack weights as
// wt[((k4*3 + gate)*256 + h)*4 + j] = w[(gate*256 + h)*256 + k4*4 + j]
__global__ __launch_bounds__(256) void k_prep(
    const int* __restrict__ batch_idxs, const int* __restrict__ actor_ids,
    const int* __restrict__ story_stop, int n_stop,
    const float* __restrict__ w_ih, const float* __restrict__ w_hh,
    int* rowaid, int* rowstop, float* wtI, float* wtH) {
    const int t = threadIdx.x;
    if (blockIdx.x < 8) {
        int g = blockIdx.x * 256 + t;
        int row = batch_idxs[g];
        int a = actor_ids[row];
        a = a < 0 ? 0 : (a > CAST - 1 ? CAST - 1 : a);
        rowaid[row] = a;
        if (g < n_stop) rowstop[story_stop[g]] = 1;
    } else {
        int id  = blockIdx.x - 8;          // 0..383
        int mat = id / 192;                // 0: w_ih, 1: w_hh
        int rem = id % 192;
        int g   = rem / 64;
        int k4  = rem % 64;
        const float* w = mat ? w_hh : w_ih;
        float*      wt = mat ? wtH  : wtI;
        float4 wv = *(const float4*)(w + ((size_t)(g * HDIM + t) * INDIM + k4 * 4));
        *(float4*)(wt + ((size_t)((k4 * 3 + g) * HDIM + t)) * 4) = wv;
    }
}

// ---------------- fused GRU + state copy (reverse row order) ----------------
// blocks [0, GRU_BLOCKS): GRU on BM rows each.
// blocks [GRU_BLOCKS, +B_TOTAL): copy one batch row each, rows processed in
//   DESCENDING address order (MALL-hot half first). Normal temporal loads
//   (retain state in MALL), NT stores (don't waste MALL on out_state).
__global__ __launch_bounds__(256) void k_main(
    const float* __restrict__ x, const int* __restrict__ batch_idxs,
    const int* __restrict__ actor_ids, const float* __restrict__ state,
    const float* __restrict__ wtI, const float* __restrict__ wtH,
    const float* __restrict__ b_ih, const float* __restrict__ b_hh,
    const int* __restrict__ rowaid, const int* __restrict__ rowstop,
    float* __restrict__ out_sel, float* __restrict__ out_state) {
    __shared__ float xs[BM][INDIM];
    __shared__ float ss[BM][HDIM];
    const int h = threadIdx.x;

    if (blockIdx.x < GRU_BLOCKS) {
        const int b0 = blockIdx.x * BM;
        #pragma unroll
        for (int r = 0; r < BM; ++r) {
            int g  = b0 + r;
            int bi = batch_idxs[g];
            int a  = actor_ids[bi];
            a = a < 0 ? 0 : (a > CAST - 1 ? CAST - 1 : a);
            xs[r][h] = x[(size_t)g * INDIM + h];
            ss[r][h] = state[((size_t)bi * CAST + a) * HDIM + h];
        }
        __syncthreads();

        float air[BM], aiz[BM], ain[BM], ahr[BM], ahz[BM], ahn[BM];
        #pragma unroll
        for (int r = 0; r < BM; ++r) { air[r]=0.f; aiz[r]=0.f; ain[r]=0.f; ahr[r]=0.f; ahz[r]=0.f; ahn[r]=0.f; }

        const float4* __restrict__ wtI4 = (const float4*)wtI;
        const float4* __restrict__ wtH4 = (const float4*)wtH;

        for (int k4 = 0; k4 < INDIM / 4; ++k4) {
            float4 wir = wtI4[(k4 * 3 + 0) * HDIM + h];
            float4 wiz = wtI4[(k4 * 3 + 1) * HDIM + h];
            float4 win = wtI4[(k4 * 3 + 2) * HDIM + h];
            float4 whr = wtH4[(k4 * 3 + 0) * HDIM + h];
            float4 whz = wtH4[(k4 * 3 + 1) * HDIM + h];
            float4 whn = wtH4[(k4 * 3 + 2) * HDIM + h];
            #pragma unroll
            for (int r = 0; r < BM; ++r) {
                float4 xv = *(const float4*)(&xs[r][k4 * 4]);
                float4 sv = *(const float4*)(&ss[r][k4 * 4]);
                air[r] = fmaf(xv.w, wir.w, fmaf(xv.z, wir.z, fmaf(xv.y, wir.y, fmaf(xv.x, wir.x, air[r]))));
                aiz[r] = fmaf(xv.w, wiz.w, fmaf(xv.z, wiz.z, fmaf(xv.y, wiz.y, fmaf(xv.x, wiz.x, aiz[r]))));
                ain[r] = fmaf(xv.w, win.w, fmaf(xv.z, win.z, fmaf(xv.y, win.y, fmaf(xv.x, win.x, ain[r]))));
                ahr[r] = fmaf(sv.w, whr.w, fmaf(sv.z, whr.z, fmaf(sv.y, whr.y, fmaf(sv.x, whr.x, ahr[r]))));
                ahz[r] = fmaf(sv.w, whz.w, fmaf(sv.z, whz.z, fmaf(sv.y, whz.y, fmaf(sv.x, whz.x, ahz[r]))));
                ahn[r] = fmaf(sv.w, whn.w, fmaf(sv.z, whn.z, fmaf(sv.y, whn.y, fmaf(sv.x, whn.x, ahn[r]))));
            }
        }

        const float bir = b_ih[h], biz = b_ih[HDIM + h], bin = b_ih[2 * HDIM + h];
        const float bhr = b_hh[h], bhz = b_hh[HDIM + h], bhn = b_hh[2 * HDIM + h];

        #pragma unroll
        for (int r = 0; r < BM; ++r) {
            int g  = b0 + r;
            int bi = batch_idxs[g];
            int a  = actor_ids[bi];
            a = a < 0 ? 0 : (a > CAST - 1 ? CAST - 1 : a);
            float ir = air[r] + bir, iz = aiz[r] + biz, inn = ain[r] + bin;
            float hr = ahr[r] + bhr, hz = ahz[r] + bhz, hn = ahn[r] + bhn;
            float rr = 1.f / (1.f + __expf(-(ir + hr)));
            float zz = 1.f / (1.f + __expf(-(iz + hz)));
            float nn = tanhf(inn + rr * hn);
            float val = (1.f - zz) * nn + zz * ss[r][h];
            out_sel[(size_t)g * HDIM + h] = val;
            if (!rowstop[bi]) out_state[((size_t)bi * CAST + a) * HDIM + h] = val;
        }
    } else {
        // Reverse order: earliest-dispatched copy blocks take the HIGHEST rows
        // (most recently touched by the previous replay -> MALL-resident).
        const int  b = B_TOTAL - 1 - (blockIdx.x - GRU_BLOCKS);
        const int  t = threadIdx.x;
        const long base = (long)b * ROW_F4;
        fx4* __restrict__ dp = (fx4*)out_state + base + t;

        if (rowstop[b]) {
            const fx4 z = (fx4)(0.f);
            #pragma unroll
            for (int j = 0; j < 32; ++j)
                __builtin_nontemporal_store(z, dp + j * 256);
            return;
        }

        const fx4* __restrict__ sp = (const fx4*)state + base + t;
        // slot c covered at iteration j by c = j*4 + (t>>6): wave-scalar skip.
        const int aid = __builtin_amdgcn_readfirstlane(rowaid[b]);
        const int w   = __builtin_amdgcn_readfirstlane(t >> 6);
        const int jskip = ((aid & 3) == w) ? (aid >> 2) : -1;

        #pragma unroll
        for (int g2 = 0; g2 < 2; ++g2) {
            fx4 d[16];
            #pragma unroll
            for (int i = 0; i < 16; ++i)
                d[i] = sp[(g2 * 16 + i) * 256];          // temporal load
            #pragma unroll
            for (int i = 0; i < 16; ++i) {
                if (g2 * 16 + i != jskip)
                    __builtin_nontemporal_store(d[i], dp + (g2 * 16 + i) * 256);
            }
        }
    }
}

extern "C" void kernel_launch(void* const* d_in, const int* in_sizes, int n_in,
                              void* d_out, int out_size, void* d_ws, size_t ws_size,
                              hipStream_t stream) {
    const float* x          = (const float*)d_in[0];
    const int*   batch_idxs = (const int*)d_in[1];
    const int*   actor_ids  = (const int*)d_in[2];
    const int*   story_stop = (const int*)d_in[3];
    const float* state      = (const float*)d_in[4];
    const float* w_ih       = (const float*)d_in[5];
    const float* w_hh       = (const float*)d_in[6];
    const float* b_ih       = (const float*)d_in[7];
    const float* b_hh       = (const float*)d_in[8];
    const int    n_stop     = in_sizes[3];

    float* out_sel   = (float*)d_out;
    float* out_state = out_sel + (size_t)B_TOTAL * HDIM;

    int*   rowaid  = (int*)d_ws;
    int*   rowstop = rowaid + B_TOTAL;
    float* wtI     = (float*)((char*)d_ws + 16384);
    float* wtH     = wtI + (size_t)3 * HDIM * INDIM;

    hipMemsetAsync(rowstop, 0, B_TOTAL * sizeof(int), stream);
    k_prep<<<8 + 384, 256, 0, stream>>>(batch_idxs, actor_ids, story_stop, n_stop,
                                        w_ih, w_hh, rowaid, rowstop, wtI, wtH);
    k_main<<<GRU_BLOCKS + B_TOTAL, 256, 0, stream>>>(
        x, batch_idxs, actor_ids, state, wtI, wtH, b_ih, b_hh,
        rowaid, rowstop, out_sel, out_state);
}